// Round 7
// baseline (560.150 us; speedup 1.0000x reference)
//
#include <hip/hip_runtime.h>

constexpr int DFEAT  = 64;
constexpr int KSTEPS = 10;
constexpr float ALPHA = 0.1f;
constexpr int PAD    = 8;     // CSR row length padded to multiple of 8
constexpr int NPART  = 8;     // dst-range partitions (one per XCD)

constexpr int SCAN_T    = 256;
constexpr int SCAN_I    = 4;
constexpr int SCAN_TILE = SCAN_T * SCAN_I;  // 1024

typedef unsigned int u32;
typedef __attribute__((ext_vector_type(4))) unsigned int u32x4;

// bf16 pack helper (round-to-nearest-even), returns low 16 bits
__device__ inline u32 f2bf(float f) {
    u32 u = __float_as_uint(f);
    return ((u + 0x7fffu + ((u >> 16) & 1u)) >> 16) & 0xFFFFu;
}

// ---- histogram, dst-range partitioned: blockIdx&7 owns one-eighth of node ids ----
__global__ void k_hist(const int* __restrict__ col, int* __restrict__ deg,
                       int E, int N) {
    int part = blockIdx.x & (NPART - 1);
    int blk  = blockIdx.x >> 3;
    int nblk = gridDim.x >> 3;
    int chunk = (N + NPART - 1) / NPART;
    int lo = part * chunk, hi = min(N, lo + chunk);
    int stride = nblk * blockDim.x;
    for (int e = blk * blockDim.x + threadIdx.x; e < E; e += stride) {
        int c = __builtin_nontemporal_load(&col[e]);
        if (c >= lo && c < hi) atomicAdd(&deg[c], 1);
    }
}

// ---- dinv + padded degree ----
__global__ void k_dinv(const int* __restrict__ deg, float* __restrict__ dinv,
                       int* __restrict__ dpad, int N) {
    int stride = gridDim.x * blockDim.x;
    for (int i = blockIdx.x * blockDim.x + threadIdx.x; i < N; i += stride) {
        int d = deg[i];
        dinv[i] = (d > 0) ? rsqrtf((float)d) : 0.0f;
        dpad[i] = (d + (PAD - 1)) & ~(PAD - 1);
    }
}

// ---- scan phase 1 (exclusive scan of dpad) ----
__global__ void k_scan1(const int* __restrict__ in, int* __restrict__ out,
                        int* __restrict__ bsum, int n) {
    __shared__ int s[SCAN_T];
    int tid  = threadIdx.x;
    int base = blockIdx.x * SCAN_TILE + tid * SCAN_I;
    int v[SCAN_I];
    int sum = 0;
#pragma unroll
    for (int j = 0; j < SCAN_I; ++j) {
        v[j] = (base + j < n) ? in[base + j] : 0;
        sum += v[j];
    }
    s[tid] = sum;
    __syncthreads();
    for (int ofs = 1; ofs < SCAN_T; ofs <<= 1) {
        int t = (tid >= ofs) ? s[tid - ofs] : 0;
        __syncthreads();
        s[tid] += t;
        __syncthreads();
    }
    int excl = (tid == 0) ? 0 : s[tid - 1];
    if (tid == SCAN_T - 1) bsum[blockIdx.x] = s[tid];
#pragma unroll
    for (int j = 0; j < SCAN_I; ++j) {
        if (base + j < n) out[base + j] = excl;
        excl += v[j];
    }
}

// ---- scan phase 2 ----
__global__ void k_scan2(int* __restrict__ bsum, int nb) {
    if (threadIdx.x == 0 && blockIdx.x == 0) {
        int acc = 0;
        for (int i = 0; i < nb; ++i) { int t = bsum[i]; bsum[i] = acc; acc += t; }
    }
}

// ---- scan phase 3 ----
__global__ void k_scan3(int* __restrict__ offs, int* __restrict__ cursor,
                        const int* __restrict__ bsum, int n) {
    int add  = bsum[blockIdx.x];
    int base = blockIdx.x * SCAN_TILE + threadIdx.x * SCAN_I;
#pragma unroll
    for (int j = 0; j < SCAN_I; ++j) {
        int i = base + j;
        if (i < n) { int o = offs[i] + add; offs[i] = o; cursor[i] = o; }
    }
}

// ---- fill CSR, dst-range partitioned: meta[pos] = {w 15-bit << 17 | src 17-bit} ----
// All stores for a given dst range come from one blockIdx%8 class (≈ one XCD),
// so meta lines stay in that XCD's L2 and write back once.
__global__ void k_fill(const int* __restrict__ row, const int* __restrict__ col,
                       const float* __restrict__ dinv, int* __restrict__ cursor,
                       u32* __restrict__ meta, int E, int N) {
    int part = blockIdx.x & (NPART - 1);
    int blk  = blockIdx.x >> 3;
    int nblk = gridDim.x >> 3;
    int chunk = (N + NPART - 1) / NPART;
    int lo = part * chunk, hi = min(N, lo + chunk);
    int stride = nblk * blockDim.x;
    for (int e = blk * blockDim.x + threadIdx.x; e < E; e += stride) {
        int c = __builtin_nontemporal_load(&col[e]);
        if (c < lo || c >= hi) continue;
        int r = __builtin_nontemporal_load(&row[e]);
        int pos = atomicAdd(&cursor[c], 1);
        float w = dinv[r] * dinv[c];                     // in [0,1]
        u32 wq = (u32)__float2int_rn(w * 32768.0f);
        if (wq > 32767u) wq = 32767u;
        meta[pos] = (wq << 17) | (u32)r;
    }
}

// ---- x (fp32) -> xb (bf16 packed, 32 u32 per row) ----
__global__ void k_cvt(const float* __restrict__ x, u32* __restrict__ xb, int n8) {
    int stride = gridDim.x * blockDim.x;
    const float4* x4 = (const float4*)x;
    u32x4* o4 = (u32x4*)xb;
    for (int i = blockIdx.x * blockDim.x + threadIdx.x; i < n8; i += stride) {
        float4 a = x4[2 * i], b = x4[2 * i + 1];
        u32x4 o;
        o.x = (f2bf(a.y) << 16) | f2bf(a.x);
        o.y = (f2bf(a.w) << 16) | f2bf(a.z);
        o.z = (f2bf(b.y) << 16) | f2bf(b.x);
        o.w = (f2bf(b.w) << 16) | f2bf(b.z);
        o4[i] = o;
    }
}

// ---- propagate: one wave per dst node; 8 lanes per edge, 8 edges per gather ----
// group g = lane>>3 handles edge j+g; lane covers features l*8..l*8+7 (l=lane&7).
// non-LAST: teleport from bf16 xb, bf16 out. LAST: teleport from fp32 x, fp32 out.
template<bool LAST>
__global__ void __launch_bounds__(256) k_prop(
    const int* __restrict__ offs, const int* __restrict__ dpad,
    const u32* __restrict__ meta, const u32* __restrict__ hsrc,
    const float* __restrict__ x, const u32* __restrict__ xb,
    void* __restrict__ hdst, int N) {
    int wid  = (int)((blockIdx.x * blockDim.x + threadIdx.x) >> 6);
    int lane = threadIdx.x & 63;
    if (wid >= N) return;
    int g = lane >> 3, l = lane & 7;
    int j   = offs[wid];
    int end = j + dpad[wid];          // multiple of 8

    const u32x4* h4 = (const u32x4*)hsrc;   // row r = h4[r*8 .. r*8+7]
    float a0 = 0.f, a1 = 0.f, a2 = 0.f, a3 = 0.f,
          a4 = 0.f, a5 = 0.f, a6 = 0.f, a7 = 0.f;

    for (; j + 16 <= end; j += 16) {       // 16 edges in flight (2 gathers/wave)
        u32 m0 = __builtin_nontemporal_load(&meta[j + g]);
        u32 m1 = __builtin_nontemporal_load(&meta[j + 8 + g]);
        u32x4 q0 = h4[(size_t)(m0 & 0x1FFFFu) * 8 + l];
        u32x4 q1 = h4[(size_t)(m1 & 0x1FFFFu) * 8 + l];
        float w0 = (float)(m0 >> 17) * (1.0f / 32768.0f);
        float w1 = (float)(m1 >> 17) * (1.0f / 32768.0f);
        a0 += w0 * __uint_as_float(q0.x << 16);
        a1 += w0 * __uint_as_float(q0.x & 0xFFFF0000u);
        a2 += w0 * __uint_as_float(q0.y << 16);
        a3 += w0 * __uint_as_float(q0.y & 0xFFFF0000u);
        a4 += w0 * __uint_as_float(q0.z << 16);
        a5 += w0 * __uint_as_float(q0.z & 0xFFFF0000u);
        a6 += w0 * __uint_as_float(q0.w << 16);
        a7 += w0 * __uint_as_float(q0.w & 0xFFFF0000u);
        a0 += w1 * __uint_as_float(q1.x << 16);
        a1 += w1 * __uint_as_float(q1.x & 0xFFFF0000u);
        a2 += w1 * __uint_as_float(q1.y << 16);
        a3 += w1 * __uint_as_float(q1.y & 0xFFFF0000u);
        a4 += w1 * __uint_as_float(q1.z << 16);
        a5 += w1 * __uint_as_float(q1.z & 0xFFFF0000u);
        a6 += w1 * __uint_as_float(q1.w << 16);
        a7 += w1 * __uint_as_float(q1.w & 0xFFFF0000u);
    }
    if (j < end) {                          // one trailing 8-edge chunk
        u32 m0 = __builtin_nontemporal_load(&meta[j + g]);
        u32x4 q0 = h4[(size_t)(m0 & 0x1FFFFu) * 8 + l];
        float w0 = (float)(m0 >> 17) * (1.0f / 32768.0f);
        a0 += w0 * __uint_as_float(q0.x << 16);
        a1 += w0 * __uint_as_float(q0.x & 0xFFFF0000u);
        a2 += w0 * __uint_as_float(q0.y << 16);
        a3 += w0 * __uint_as_float(q0.y & 0xFFFF0000u);
        a4 += w0 * __uint_as_float(q0.z << 16);
        a5 += w0 * __uint_as_float(q0.z & 0xFFFF0000u);
        a6 += w0 * __uint_as_float(q0.w << 16);
        a7 += w0 * __uint_as_float(q0.w & 0xFFFF0000u);
    }

    // reduce across the 8 groups (lane bits 3..5)
#pragma unroll
    for (int mask = 8; mask <= 32; mask <<= 1) {
        a0 += __shfl_xor(a0, mask); a1 += __shfl_xor(a1, mask);
        a2 += __shfl_xor(a2, mask); a3 += __shfl_xor(a3, mask);
        a4 += __shfl_xor(a4, mask); a5 += __shfl_xor(a5, mask);
        a6 += __shfl_xor(a6, mask); a7 += __shfl_xor(a7, mask);
    }

    if (g == 0) {                           // 8 lanes cover the 64-feat row
        if (LAST) {
            size_t base = (size_t)wid * DFEAT + (size_t)l * 8;
            float4 xa = *(const float4*)&x[base];
            float4 xc = *(const float4*)&x[base + 4];
            float r0 = (1.0f - ALPHA) * a0 + ALPHA * xa.x;
            float r1 = (1.0f - ALPHA) * a1 + ALPHA * xa.y;
            float r2 = (1.0f - ALPHA) * a2 + ALPHA * xa.z;
            float r3 = (1.0f - ALPHA) * a3 + ALPHA * xa.w;
            float r4 = (1.0f - ALPHA) * a4 + ALPHA * xc.x;
            float r5 = (1.0f - ALPHA) * a5 + ALPHA * xc.y;
            float r6 = (1.0f - ALPHA) * a6 + ALPHA * xc.z;
            float r7 = (1.0f - ALPHA) * a7 + ALPHA * xc.w;
            float* o = (float*)hdst;
            *(float4*)&o[base]     = make_float4(r0, r1, r2, r3);
            *(float4*)&o[base + 4] = make_float4(r4, r5, r6, r7);
        } else {
            u32x4 t = ((const u32x4*)xb)[(size_t)wid * 8 + l];
            float r0 = (1.0f - ALPHA) * a0 + ALPHA * __uint_as_float(t.x << 16);
            float r1 = (1.0f - ALPHA) * a1 + ALPHA * __uint_as_float(t.x & 0xFFFF0000u);
            float r2 = (1.0f - ALPHA) * a2 + ALPHA * __uint_as_float(t.y << 16);
            float r3 = (1.0f - ALPHA) * a3 + ALPHA * __uint_as_float(t.y & 0xFFFF0000u);
            float r4 = (1.0f - ALPHA) * a4 + ALPHA * __uint_as_float(t.z << 16);
            float r5 = (1.0f - ALPHA) * a5 + ALPHA * __uint_as_float(t.z & 0xFFFF0000u);
            float r6 = (1.0f - ALPHA) * a6 + ALPHA * __uint_as_float(t.w << 16);
            float r7 = (1.0f - ALPHA) * a7 + ALPHA * __uint_as_float(t.w & 0xFFFF0000u);
            u32x4 o;
            o.x = (f2bf(r1) << 16) | f2bf(r0);
            o.y = (f2bf(r3) << 16) | f2bf(r2);
            o.z = (f2bf(r5) << 16) | f2bf(r4);
            o.w = (f2bf(r7) << 16) | f2bf(r6);
            ((u32x4*)hdst)[(size_t)wid * 8 + l] = o;
        }
    }
}

extern "C" void kernel_launch(void* const* d_in, const int* in_sizes, int n_in,
                              void* d_out, int out_size, void* d_ws, size_t ws_size,
                              hipStream_t stream) {
    const float* x  = (const float*)d_in[0];
    const int*   ei = (const int*)d_in[1];
    const int N = in_sizes[0] / DFEAT;   // 100000 (< 2^17, fits packed src)
    const int E = in_sizes[1] / 2;
    const int* row = ei;       // sources
    const int* col = ei + E;   // destinations

    char* ws = (char*)d_ws;
    auto align256 = [](size_t v) { return (v + 255) & ~(size_t)255; };
    size_t off = 0;
    int* deg = (int*)(ws + off);        off += align256((size_t)N * 4);
    int* dpad = (int*)(ws + off);       off += align256((size_t)N * 4);
    float* dinv = (float*)(ws + off);   off += align256((size_t)N * 4);
    int* offs = (int*)(ws + off);       off += align256((size_t)N * 4);
    int* cursor = (int*)(ws + off);     off += align256((size_t)N * 4);
    int* bsum = (int*)(ws + off);       off += align256((size_t)4096);
    size_t metaCap = (size_t)E + (size_t)(PAD - 1) * N;
    u32* meta = (u32*)(ws + off);       off += align256(metaCap * 4);
    u32* xb = (u32*)(ws + off);         off += align256((size_t)N * 32 * 4);  // bf16 rows
    u32* hA = (u32*)(ws + off);         off += align256((size_t)N * 32 * 4);
    u32* hB = (u32*)(ws + off);         off += align256((size_t)N * 32 * 4);

    float* out = (float*)d_out;

    const int BLK = 256;
    const int gridN = (N + BLK - 1) / BLK;
    const int nb    = (N + SCAN_TILE - 1) / SCAN_TILE;
    const int n8    = N * DFEAT / 8;
    const int gridC = (n8 + BLK - 1) / BLK;
    const int gridProp = (N + 3) / 4;    // 4 waves/block, 1 wave/node
    const int gridPart = NPART * 256;    // 8 partition classes x 256 blocks

    hipMemsetAsync(deg, 0, (size_t)N * 4, stream);
    hipMemsetAsync(meta, 0, metaCap * 4, stream);   // pads -> src=0, w=0
    k_hist <<<gridPart, BLK, 0, stream>>>(col, deg, E, N);
    k_dinv <<<gridN, BLK, 0, stream>>>(deg, dinv, dpad, N);
    k_scan1<<<nb, SCAN_T, 0, stream>>>(dpad, offs, bsum, N);
    k_scan2<<<1, 64, 0, stream>>>(bsum, nb);
    k_scan3<<<nb, SCAN_T, 0, stream>>>(offs, cursor, bsum, N);
    k_fill <<<gridPart, BLK, 0, stream>>>(row, col, dinv, cursor, meta, E, N);
    k_cvt  <<<gridC, BLK, 0, stream>>>(x, xb, n8);

    // k=0: xb -> hA; then ping-pong; k=9 (LAST): -> out in fp32
    u32* bufs[2] = { hA, hB };
    for (int k = 0; k < KSTEPS; ++k) {
        const u32* src = (k == 0) ? xb : bufs[(k + 1) & 1];
        if (k < KSTEPS - 1) {
            k_prop<false><<<gridProp, BLK, 0, stream>>>(offs, dpad, meta, src, x, xb,
                                                        (void*)bufs[k & 1], N);
        } else {
            k_prop<true><<<gridProp, BLK, 0, stream>>>(offs, dpad, meta, src, x, xb,
                                                       (void*)out, N);
        }
    }
    (void)ws_size; (void)n_in; (void)out_size;
}

// Round 8
// 417.468 us; speedup vs baseline: 1.3418x; 1.3418x over previous
//
#include <hip/hip_runtime.h>

constexpr int DFEAT  = 64;
constexpr int KSTEPS = 10;
constexpr float ALPHA = 0.1f;
constexpr int PAD    = 4;     // CSR row length padded to multiple of 4

constexpr int SCAN_T    = 256;
constexpr int SCAN_I    = 4;
constexpr int SCAN_TILE = SCAN_T * SCAN_I;  // 1024

typedef unsigned int u32;
typedef __attribute__((ext_vector_type(4))) unsigned int u32x4;

// bf16 pack helper (round-to-nearest-even), returns low 16 bits
__device__ inline u32 f2bf(float f) {
    u32 u = __float_as_uint(f);
    return ((u + 0x7fffu + ((u >> 16) & 1u)) >> 16) & 0xFFFFu;
}
__device__ inline float bfLO(u32 v) { return __uint_as_float(v << 16); }
__device__ inline float bfHI(u32 v) { return __uint_as_float(v & 0xFFFF0000u); }

// ---- histogram: deg[col[e]] += 1 ----
__global__ void k_hist(const int* __restrict__ col, int* __restrict__ deg, int E) {
    int stride = gridDim.x * blockDim.x;
    for (int e = blockIdx.x * blockDim.x + threadIdx.x; e < E; e += stride)
        atomicAdd(&deg[col[e]], 1);
}

// ---- dinv + padded degree ----
__global__ void k_dinv(const int* __restrict__ deg, float* __restrict__ dinv,
                       int* __restrict__ dpad, int N) {
    int stride = gridDim.x * blockDim.x;
    for (int i = blockIdx.x * blockDim.x + threadIdx.x; i < N; i += stride) {
        int d = deg[i];
        dinv[i] = (d > 0) ? rsqrtf((float)d) : 0.0f;
        dpad[i] = (d + (PAD - 1)) & ~(PAD - 1);
    }
}

// ---- scan phase 1 (exclusive scan of dpad) ----
__global__ void k_scan1(const int* __restrict__ in, int* __restrict__ out,
                        int* __restrict__ bsum, int n) {
    __shared__ int s[SCAN_T];
    int tid  = threadIdx.x;
    int base = blockIdx.x * SCAN_TILE + tid * SCAN_I;
    int v[SCAN_I];
    int sum = 0;
#pragma unroll
    for (int j = 0; j < SCAN_I; ++j) {
        v[j] = (base + j < n) ? in[base + j] : 0;
        sum += v[j];
    }
    s[tid] = sum;
    __syncthreads();
    for (int ofs = 1; ofs < SCAN_T; ofs <<= 1) {
        int t = (tid >= ofs) ? s[tid - ofs] : 0;
        __syncthreads();
        s[tid] += t;
        __syncthreads();
    }
    int excl = (tid == 0) ? 0 : s[tid - 1];
    if (tid == SCAN_T - 1) bsum[blockIdx.x] = s[tid];
#pragma unroll
    for (int j = 0; j < SCAN_I; ++j) {
        if (base + j < n) out[base + j] = excl;
        excl += v[j];
    }
}

// ---- scan phase 2 ----
__global__ void k_scan2(int* __restrict__ bsum, int nb) {
    if (threadIdx.x == 0 && blockIdx.x == 0) {
        int acc = 0;
        for (int i = 0; i < nb; ++i) { int t = bsum[i]; bsum[i] = acc; acc += t; }
    }
}

// ---- scan phase 3 ----
__global__ void k_scan3(int* __restrict__ offs, int* __restrict__ cursor,
                        const int* __restrict__ bsum, int n) {
    int add  = bsum[blockIdx.x];
    int base = blockIdx.x * SCAN_TILE + threadIdx.x * SCAN_I;
#pragma unroll
    for (int j = 0; j < SCAN_I; ++j) {
        int i = base + j;
        if (i < n) { int o = offs[i] + add; offs[i] = o; cursor[i] = o; }
    }
}

// ---- fill CSR: meta[pos] = {w 15-bit fixed << 17 | src 17-bit} ----
// pad slots stay 0 from the memset -> src=0, w=0 (contributes nothing).
__global__ void k_fill(const int* __restrict__ row, const int* __restrict__ col,
                       const float* __restrict__ dinv, int* __restrict__ cursor,
                       u32* __restrict__ meta, int E) {
    int stride = gridDim.x * blockDim.x;
    for (int e = blockIdx.x * blockDim.x + threadIdx.x; e < E; e += stride) {
        int r = row[e], c = col[e];
        int pos = atomicAdd(&cursor[c], 1);
        float w = dinv[r] * dinv[c];                     // in [0,1]
        u32 wq = (u32)__float2int_rn(w * 32768.0f);
        if (wq > 32767u) wq = 32767u;
        __builtin_nontemporal_store((wq << 17) | (u32)r, &meta[pos]);
    }
}

// ---- x (fp32) -> xb (bf16 packed, 32 u32 per row) ----
__global__ void k_cvt(const float* __restrict__ x, u32* __restrict__ xb, int n8) {
    int stride = gridDim.x * blockDim.x;
    const float4* x4 = (const float4*)x;
    u32x4* o4 = (u32x4*)xb;
    for (int i = blockIdx.x * blockDim.x + threadIdx.x; i < n8; i += stride) {
        float4 a = x4[2 * i], b = x4[2 * i + 1];
        u32x4 o;
        o.x = (f2bf(a.y) << 16) | f2bf(a.x);
        o.y = (f2bf(a.w) << 16) | f2bf(a.z);
        o.z = (f2bf(b.y) << 16) | f2bf(b.x);
        o.w = (f2bf(b.w) << 16) | f2bf(b.z);
        o4[i] = o;
    }
}

// ---- propagate: one 8-lane group per dst node; lane l covers features l*8..l*8+7.
// Each group loops over its own edges 4 at a time (one broadcast u32x4 meta load),
// 4 gathers of the full 128 B bf16 src row in flight, next meta prefetched.
// No cross-group reduce, no shfls.
template<bool LAST>
__global__ void __launch_bounds__(256) k_prop(
    const int* __restrict__ offs, const int* __restrict__ dpad,
    const u32* __restrict__ meta, const u32* __restrict__ hsrc,
    const float* __restrict__ x, const u32* __restrict__ xb,
    void* __restrict__ hdst, int N) {
    int gid = (int)((blockIdx.x * blockDim.x + threadIdx.x) >> 3);  // node id
    int l   = threadIdx.x & 7;                                      // lane in group
    if (gid >= N) return;
    int j   = offs[gid];
    int end = j + dpad[gid];          // multiple of 4

    const u32x4* h4 = (const u32x4*)hsrc;   // row r = h4[r*8 .. r*8+7]
    float a0 = 0.f, a1 = 0.f, a2 = 0.f, a3 = 0.f,
          a4 = 0.f, a5 = 0.f, a6 = 0.f, a7 = 0.f;

    if (j < end) {
        u32x4 mq = *(const u32x4*)&meta[j];           // 4 edges (broadcast in group)
        while (j < end) {
            int jn = j + 4;
            u32x4 mqn = *(const u32x4*)&meta[jn];     // prefetch (slack-allocated)
            u32x4 q0 = h4[(size_t)(mq.x & 0x1FFFFu) * 8 + l];
            u32x4 q1 = h4[(size_t)(mq.y & 0x1FFFFu) * 8 + l];
            u32x4 q2 = h4[(size_t)(mq.z & 0x1FFFFu) * 8 + l];
            u32x4 q3 = h4[(size_t)(mq.w & 0x1FFFFu) * 8 + l];
            float w0 = (float)(mq.x >> 17) * (1.0f / 32768.0f);
            float w1 = (float)(mq.y >> 17) * (1.0f / 32768.0f);
            float w2 = (float)(mq.z >> 17) * (1.0f / 32768.0f);
            float w3 = (float)(mq.w >> 17) * (1.0f / 32768.0f);
            a0 += w0 * bfLO(q0.x); a1 += w0 * bfHI(q0.x);
            a2 += w0 * bfLO(q0.y); a3 += w0 * bfHI(q0.y);
            a4 += w0 * bfLO(q0.z); a5 += w0 * bfHI(q0.z);
            a6 += w0 * bfLO(q0.w); a7 += w0 * bfHI(q0.w);
            a0 += w1 * bfLO(q1.x); a1 += w1 * bfHI(q1.x);
            a2 += w1 * bfLO(q1.y); a3 += w1 * bfHI(q1.y);
            a4 += w1 * bfLO(q1.z); a5 += w1 * bfHI(q1.z);
            a6 += w1 * bfLO(q1.w); a7 += w1 * bfHI(q1.w);
            a0 += w2 * bfLO(q2.x); a1 += w2 * bfHI(q2.x);
            a2 += w2 * bfLO(q2.y); a3 += w2 * bfHI(q2.y);
            a4 += w2 * bfLO(q2.z); a5 += w2 * bfHI(q2.z);
            a6 += w2 * bfLO(q2.w); a7 += w2 * bfHI(q2.w);
            a0 += w3 * bfLO(q3.x); a1 += w3 * bfHI(q3.x);
            a2 += w3 * bfLO(q3.y); a3 += w3 * bfHI(q3.y);
            a4 += w3 * bfLO(q3.z); a5 += w3 * bfHI(q3.z);
            a6 += w3 * bfLO(q3.w); a7 += w3 * bfHI(q3.w);
            mq = mqn; j = jn;
        }
    }

    if (LAST) {
        size_t base = (size_t)gid * DFEAT + (size_t)l * 8;
        float4 xa = *(const float4*)&x[base];
        float4 xc = *(const float4*)&x[base + 4];
        float r0 = (1.0f - ALPHA) * a0 + ALPHA * xa.x;
        float r1 = (1.0f - ALPHA) * a1 + ALPHA * xa.y;
        float r2 = (1.0f - ALPHA) * a2 + ALPHA * xa.z;
        float r3 = (1.0f - ALPHA) * a3 + ALPHA * xa.w;
        float r4 = (1.0f - ALPHA) * a4 + ALPHA * xc.x;
        float r5 = (1.0f - ALPHA) * a5 + ALPHA * xc.y;
        float r6 = (1.0f - ALPHA) * a6 + ALPHA * xc.z;
        float r7 = (1.0f - ALPHA) * a7 + ALPHA * xc.w;
        float* o = (float*)hdst;
        *(float4*)&o[base]     = make_float4(r0, r1, r2, r3);
        *(float4*)&o[base + 4] = make_float4(r4, r5, r6, r7);
    } else {
        u32x4 t = ((const u32x4*)xb)[(size_t)gid * 8 + l];
        float r0 = (1.0f - ALPHA) * a0 + ALPHA * bfLO(t.x);
        float r1 = (1.0f - ALPHA) * a1 + ALPHA * bfHI(t.x);
        float r2 = (1.0f - ALPHA) * a2 + ALPHA * bfLO(t.y);
        float r3 = (1.0f - ALPHA) * a3 + ALPHA * bfHI(t.y);
        float r4 = (1.0f - ALPHA) * a4 + ALPHA * bfLO(t.z);
        float r5 = (1.0f - ALPHA) * a5 + ALPHA * bfHI(t.z);
        float r6 = (1.0f - ALPHA) * a6 + ALPHA * bfLO(t.w);
        float r7 = (1.0f - ALPHA) * a7 + ALPHA * bfHI(t.w);
        u32x4 o;
        o.x = (f2bf(r1) << 16) | f2bf(r0);
        o.y = (f2bf(r3) << 16) | f2bf(r2);
        o.z = (f2bf(r5) << 16) | f2bf(r4);
        o.w = (f2bf(r7) << 16) | f2bf(r6);
        ((u32x4*)hdst)[(size_t)gid * 8 + l] = o;
    }
}

extern "C" void kernel_launch(void* const* d_in, const int* in_sizes, int n_in,
                              void* d_out, int out_size, void* d_ws, size_t ws_size,
                              hipStream_t stream) {
    const float* x  = (const float*)d_in[0];
    const int*   ei = (const int*)d_in[1];
    const int N = in_sizes[0] / DFEAT;   // 100000 (< 2^17, fits packed src)
    const int E = in_sizes[1] / 2;
    const int* row = ei;       // sources
    const int* col = ei + E;   // destinations

    char* ws = (char*)d_ws;
    auto align256 = [](size_t v) { return (v + 255) & ~(size_t)255; };
    size_t off = 0;
    int* deg = (int*)(ws + off);        off += align256((size_t)N * 4);
    int* dpad = (int*)(ws + off);       off += align256((size_t)N * 4);
    float* dinv = (float*)(ws + off);   off += align256((size_t)N * 4);
    int* offs = (int*)(ws + off);       off += align256((size_t)N * 4);
    int* cursor = (int*)(ws + off);     off += align256((size_t)N * 4);
    int* bsum = (int*)(ws + off);       off += align256((size_t)4096);
    size_t metaCap = (size_t)E + (size_t)(PAD - 1) * N + 16;  // +16 prefetch slack
    u32* meta = (u32*)(ws + off);       off += align256(metaCap * 4);
    u32* xb = (u32*)(ws + off);         off += align256((size_t)N * 32 * 4);  // bf16 rows
    u32* hA = (u32*)(ws + off);         off += align256((size_t)N * 32 * 4);
    u32* hB = (u32*)(ws + off);         off += align256((size_t)N * 32 * 4);

    float* out = (float*)d_out;

    const int BLK = 256;
    const int gridE = (E + BLK - 1) / BLK;
    const int gridN = (N + BLK - 1) / BLK;
    const int nb    = (N + SCAN_TILE - 1) / SCAN_TILE;
    const int n8    = N * DFEAT / 8;
    const int gridC = (n8 + BLK - 1) / BLK;
    const int gridProp = (N * 8 + BLK - 1) / BLK;   // 8 threads per node

    hipMemsetAsync(deg, 0, (size_t)N * 4, stream);
    hipMemsetAsync(meta, 0, metaCap * 4, stream);   // pads -> src=0, w=0
    k_hist <<<gridE, BLK, 0, stream>>>(col, deg, E);
    k_dinv <<<gridN, BLK, 0, stream>>>(deg, dinv, dpad, N);
    k_scan1<<<nb, SCAN_T, 0, stream>>>(dpad, offs, bsum, N);
    k_scan2<<<1, 64, 0, stream>>>(bsum, nb);
    k_scan3<<<nb, SCAN_T, 0, stream>>>(offs, cursor, bsum, N);
    k_fill <<<gridE, BLK, 0, stream>>>(row, col, dinv, cursor, meta, E);
    k_cvt  <<<gridC, BLK, 0, stream>>>(x, xb, n8);

    // k=0: xb -> hA; then ping-pong; k=9 (LAST): -> out in fp32
    u32* bufs[2] = { hA, hB };
    for (int k = 0; k < KSTEPS; ++k) {
        const u32* src = (k == 0) ? xb : bufs[(k + 1) & 1];
        if (k < KSTEPS - 1) {
            k_prop<false><<<gridProp, BLK, 0, stream>>>(offs, dpad, meta, src, x, xb,
                                                        (void*)bufs[k & 1], N);
        } else {
            k_prop<true><<<gridProp, BLK, 0, stream>>>(offs, dpad, meta, src, x, xb,
                                                       (void*)out, N);
        }
    }
    (void)ws_size; (void)n_in; (void)out_size;
}

// Round 9
// 393.469 us; speedup vs baseline: 1.4236x; 1.0610x over previous
//
#include <hip/hip_runtime.h>

constexpr int DFEAT  = 64;
constexpr int KSTEPS = 10;
constexpr float ALPHA = 0.1f;
constexpr int PAD    = 4;       // CSR row length padded to multiple of 4
constexpr int BSHIFT = 8;       // 256 nodes per dst bucket
constexpr int MAXBUCK = 512;    // max buckets (N <= 131072)

constexpr int SCAN_T    = 256;
constexpr int SCAN_I    = 4;
constexpr int SCAN_TILE = SCAN_T * SCAN_I;  // 1024

typedef unsigned int u32;
typedef __attribute__((ext_vector_type(4))) unsigned int u32x4;

// bf16 pack helper (round-to-nearest-even), returns low 16 bits
__device__ inline u32 f2bf(float f) {
    u32 u = __float_as_uint(f);
    return ((u + 0x7fffu + ((u >> 16) & 1u)) >> 16) & 0xFFFFu;
}
__device__ inline float bfLO(u32 v) { return __uint_as_float(v << 16); }
__device__ inline float bfHI(u32 v) { return __uint_as_float(v & 0xFFFF0000u); }

// ---- histogram: deg[col[e]] += 1 ----
__global__ void k_hist(const int* __restrict__ col, int* __restrict__ deg, int E) {
    int stride = gridDim.x * blockDim.x;
    for (int e = blockIdx.x * blockDim.x + threadIdx.x; e < E; e += stride)
        atomicAdd(&deg[col[e]], 1);
}

// ---- dinv + padded degree ----
__global__ void k_dinv(const int* __restrict__ deg, float* __restrict__ dinv,
                       int* __restrict__ dpad, int N) {
    int stride = gridDim.x * blockDim.x;
    for (int i = blockIdx.x * blockDim.x + threadIdx.x; i < N; i += stride) {
        int d = deg[i];
        dinv[i] = (d > 0) ? rsqrtf((float)d) : 0.0f;
        dpad[i] = (d + (PAD - 1)) & ~(PAD - 1);
    }
}

// ---- scan phase 1 (exclusive scan of dpad) ----
__global__ void k_scan1(const int* __restrict__ in, int* __restrict__ out,
                        int* __restrict__ bsum, int n) {
    __shared__ int s[SCAN_T];
    int tid  = threadIdx.x;
    int base = blockIdx.x * SCAN_TILE + tid * SCAN_I;
    int v[SCAN_I];
    int sum = 0;
#pragma unroll
    for (int j = 0; j < SCAN_I; ++j) {
        v[j] = (base + j < n) ? in[base + j] : 0;
        sum += v[j];
    }
    s[tid] = sum;
    __syncthreads();
    for (int ofs = 1; ofs < SCAN_T; ofs <<= 1) {
        int t = (tid >= ofs) ? s[tid - ofs] : 0;
        __syncthreads();
        s[tid] += t;
        __syncthreads();
    }
    int excl = (tid == 0) ? 0 : s[tid - 1];
    if (tid == SCAN_T - 1) bsum[blockIdx.x] = s[tid];
#pragma unroll
    for (int j = 0; j < SCAN_I; ++j) {
        if (base + j < n) out[base + j] = excl;
        excl += v[j];
    }
}

// ---- scan phase 2 ----
__global__ void k_scan2(int* __restrict__ bsum, int nb) {
    if (threadIdx.x == 0 && blockIdx.x == 0) {
        int acc = 0;
        for (int i = 0; i < nb; ++i) { int t = bsum[i]; bsum[i] = acc; acc += t; }
    }
}

// ---- scan phase 3: offs += block offset ----
__global__ void k_scan3(int* __restrict__ offs, const int* __restrict__ bsum, int n) {
    int add  = bsum[blockIdx.x];
    int base = blockIdx.x * SCAN_TILE + threadIdx.x * SCAN_I;
#pragma unroll
    for (int j = 0; j < SCAN_I; ++j) {
        int i = base + j;
        if (i < n) offs[i] += add;
    }
}

// ---- per-bucket edge totals from deg (atomic-free) ----
__global__ void k_bsum(const int* __restrict__ deg, int* __restrict__ btotal, int N) {
    __shared__ int red[256];
    int b = blockIdx.x, t = threadIdx.x;
    int node = (b << BSHIFT) + t;
    red[t] = (node < N) ? deg[node] : 0;
    __syncthreads();
    for (int o = 128; o > 0; o >>= 1) {
        if (t < o) red[t] += red[t + o];
        __syncthreads();
    }
    if (t == 0) btotal[b] = red[0];
}

// ---- exclusive scan of bucket totals -> bstart; init padded cursors bcur ----
__global__ void k_bscan(const int* __restrict__ btotal, int* __restrict__ bstart,
                        int* __restrict__ bcur, int nb) {
    __shared__ int s[MAXBUCK];
    int t = threadIdx.x;
    if (t < nb) s[t] = btotal[t];
    __syncthreads();
    if (t == 0) {
        int acc = 0;
        for (int i = 0; i < nb; ++i) { int v = s[i]; s[i] = acc; acc += v; }
    }
    __syncthreads();
    if (t < nb) { bstart[t] = s[t]; bcur[t * 16] = s[t]; }   // 64B-padded cursors
}

// ---- pass A: bucket edges by dst range; per-(block,bucket) contiguous segments ----
__global__ void __launch_bounds__(256) k_bucketA(
    const int* __restrict__ row, const int* __restrict__ col,
    int* __restrict__ bcur, u32* __restrict__ bucketed,
    int E, int nb, int chunk) {
    __shared__ int hist[MAXBUCK];
    __shared__ int cur[MAXBUCK];
    int t  = threadIdx.x;
    int e0 = blockIdx.x * chunk;
    int e1 = min(E, e0 + chunk);
    for (int b = t; b < nb; b += 256) hist[b] = 0;
    __syncthreads();
    for (int e = e0 + t; e < e1; e += 256)
        atomicAdd(&hist[col[e] >> BSHIFT], 1);
    __syncthreads();
    for (int b = t; b < nb; b += 256)
        cur[b] = hist[b] ? atomicAdd(&bcur[b * 16], hist[b]) : 0;
    __syncthreads();
    for (int e = e0 + t; e < e1; e += 256) {
        int c = col[e], r = row[e];
        int rank = atomicAdd(&cur[c >> BSHIFT], 1);
        bucketed[rank] = ((u32)r << BSHIFT) | (u32)(c & ((1 << BSHIFT) - 1));
    }
}

// ---- pass B: per-bucket CSR fill; LDS cursors, bucket-local meta writes ----
__global__ void __launch_bounds__(256) k_fillB(
    const u32* __restrict__ bucketed, const int* __restrict__ bstart,
    const int* __restrict__ btotal, const int* __restrict__ offs,
    const float* __restrict__ dinv, u32* __restrict__ meta, int N) {
    __shared__ int   lcur[256];
    __shared__ float ldinv[256];
    int b = blockIdx.x, t = threadIdx.x;
    int node = (b << BSHIFT) + t;
    lcur[t]  = (node < N) ? offs[node] : 0;
    ldinv[t] = (node < N) ? dinv[node] : 0.0f;
    __syncthreads();
    int p0 = bstart[b], p1 = p0 + btotal[b];
    for (int p = p0 + t; p < p1; p += 256) {
        u32 v  = bucketed[p];
        int r  = (int)(v >> BSHIFT);
        int cl = (int)(v & 255u);
        int pos = atomicAdd(&lcur[cl], 1);
        float w = dinv[r] * ldinv[cl];            // in [0,1]
        u32 wq = (u32)__float2int_rn(w * 32768.0f);
        if (wq > 32767u) wq = 32767u;
        meta[pos] = (wq << 17) | (u32)r;
    }
}

// ---- x (fp32) -> xb (bf16 packed, 32 u32 per row) ----
__global__ void k_cvt(const float* __restrict__ x, u32* __restrict__ xb, int n8) {
    int stride = gridDim.x * blockDim.x;
    const float4* x4 = (const float4*)x;
    u32x4* o4 = (u32x4*)xb;
    for (int i = blockIdx.x * blockDim.x + threadIdx.x; i < n8; i += stride) {
        float4 a = x4[2 * i], b = x4[2 * i + 1];
        u32x4 o;
        o.x = (f2bf(a.y) << 16) | f2bf(a.x);
        o.y = (f2bf(a.w) << 16) | f2bf(a.z);
        o.z = (f2bf(b.y) << 16) | f2bf(b.x);
        o.w = (f2bf(b.w) << 16) | f2bf(b.z);
        o4[i] = o;
    }
}

// ---- propagate: one 8-lane group per dst node; lane l covers features l*8..l*8+7.
template<bool LAST>
__global__ void __launch_bounds__(256) k_prop(
    const int* __restrict__ offs, const int* __restrict__ dpad,
    const u32* __restrict__ meta, const u32* __restrict__ hsrc,
    const float* __restrict__ x, const u32* __restrict__ xb,
    void* __restrict__ hdst, int N) {
    int gid = (int)((blockIdx.x * blockDim.x + threadIdx.x) >> 3);  // node id
    int l   = threadIdx.x & 7;                                      // lane in group
    if (gid >= N) return;
    int j   = offs[gid];
    int end = j + dpad[gid];          // multiple of 4

    const u32x4* h4 = (const u32x4*)hsrc;   // row r = h4[r*8 .. r*8+7]
    float a0 = 0.f, a1 = 0.f, a2 = 0.f, a3 = 0.f,
          a4 = 0.f, a5 = 0.f, a6 = 0.f, a7 = 0.f;

    if (j < end) {
        u32x4 mq = *(const u32x4*)&meta[j];           // 4 edges (broadcast in group)
        while (j < end) {
            int jn = j + 4;
            u32x4 mqn = *(const u32x4*)&meta[jn];     // prefetch (slack-allocated)
            u32x4 q0 = h4[(size_t)(mq.x & 0x1FFFFu) * 8 + l];
            u32x4 q1 = h4[(size_t)(mq.y & 0x1FFFFu) * 8 + l];
            u32x4 q2 = h4[(size_t)(mq.z & 0x1FFFFu) * 8 + l];
            u32x4 q3 = h4[(size_t)(mq.w & 0x1FFFFu) * 8 + l];
            float w0 = (float)(mq.x >> 17) * (1.0f / 32768.0f);
            float w1 = (float)(mq.y >> 17) * (1.0f / 32768.0f);
            float w2 = (float)(mq.z >> 17) * (1.0f / 32768.0f);
            float w3 = (float)(mq.w >> 17) * (1.0f / 32768.0f);
            a0 += w0 * bfLO(q0.x); a1 += w0 * bfHI(q0.x);
            a2 += w0 * bfLO(q0.y); a3 += w0 * bfHI(q0.y);
            a4 += w0 * bfLO(q0.z); a5 += w0 * bfHI(q0.z);
            a6 += w0 * bfLO(q0.w); a7 += w0 * bfHI(q0.w);
            a0 += w1 * bfLO(q1.x); a1 += w1 * bfHI(q1.x);
            a2 += w1 * bfLO(q1.y); a3 += w1 * bfHI(q1.y);
            a4 += w1 * bfLO(q1.z); a5 += w1 * bfHI(q1.z);
            a6 += w1 * bfLO(q1.w); a7 += w1 * bfHI(q1.w);
            a0 += w2 * bfLO(q2.x); a1 += w2 * bfHI(q2.x);
            a2 += w2 * bfLO(q2.y); a3 += w2 * bfHI(q2.y);
            a4 += w2 * bfLO(q2.z); a5 += w2 * bfHI(q2.z);
            a6 += w2 * bfLO(q2.w); a7 += w2 * bfHI(q2.w);
            a0 += w3 * bfLO(q3.x); a1 += w3 * bfHI(q3.x);
            a2 += w3 * bfLO(q3.y); a3 += w3 * bfHI(q3.y);
            a4 += w3 * bfLO(q3.z); a5 += w3 * bfHI(q3.z);
            a6 += w3 * bfLO(q3.w); a7 += w3 * bfHI(q3.w);
            mq = mqn; j = jn;
        }
    }

    if (LAST) {
        size_t base = (size_t)gid * DFEAT + (size_t)l * 8;
        float4 xa = *(const float4*)&x[base];
        float4 xc = *(const float4*)&x[base + 4];
        float r0 = (1.0f - ALPHA) * a0 + ALPHA * xa.x;
        float r1 = (1.0f - ALPHA) * a1 + ALPHA * xa.y;
        float r2 = (1.0f - ALPHA) * a2 + ALPHA * xa.z;
        float r3 = (1.0f - ALPHA) * a3 + ALPHA * xa.w;
        float r4 = (1.0f - ALPHA) * a4 + ALPHA * xc.x;
        float r5 = (1.0f - ALPHA) * a5 + ALPHA * xc.y;
        float r6 = (1.0f - ALPHA) * a6 + ALPHA * xc.z;
        float r7 = (1.0f - ALPHA) * a7 + ALPHA * xc.w;
        float* o = (float*)hdst;
        *(float4*)&o[base]     = make_float4(r0, r1, r2, r3);
        *(float4*)&o[base + 4] = make_float4(r4, r5, r6, r7);
    } else {
        u32x4 t = ((const u32x4*)xb)[(size_t)gid * 8 + l];
        float r0 = (1.0f - ALPHA) * a0 + ALPHA * bfLO(t.x);
        float r1 = (1.0f - ALPHA) * a1 + ALPHA * bfHI(t.x);
        float r2 = (1.0f - ALPHA) * a2 + ALPHA * bfLO(t.y);
        float r3 = (1.0f - ALPHA) * a3 + ALPHA * bfHI(t.y);
        float r4 = (1.0f - ALPHA) * a4 + ALPHA * bfLO(t.z);
        float r5 = (1.0f - ALPHA) * a5 + ALPHA * bfHI(t.z);
        float r6 = (1.0f - ALPHA) * a6 + ALPHA * bfLO(t.w);
        float r7 = (1.0f - ALPHA) * a7 + ALPHA * bfHI(t.w);
        u32x4 o;
        o.x = (f2bf(r1) << 16) | f2bf(r0);
        o.y = (f2bf(r3) << 16) | f2bf(r2);
        o.z = (f2bf(r5) << 16) | f2bf(r4);
        o.w = (f2bf(r7) << 16) | f2bf(r6);
        ((u32x4*)hdst)[(size_t)gid * 8 + l] = o;
    }
}

extern "C" void kernel_launch(void* const* d_in, const int* in_sizes, int n_in,
                              void* d_out, int out_size, void* d_ws, size_t ws_size,
                              hipStream_t stream) {
    const float* x  = (const float*)d_in[0];
    const int*   ei = (const int*)d_in[1];
    const int N = in_sizes[0] / DFEAT;   // 100000 (< 2^17, fits packed src)
    const int E = in_sizes[1] / 2;
    const int* row = ei;       // sources
    const int* col = ei + E;   // destinations

    const int NBUCK = (N + ((1 << BSHIFT) - 1)) >> BSHIFT;   // 391 (<= MAXBUCK)

    char* ws = (char*)d_ws;
    auto align256 = [](size_t v) { return (v + 255) & ~(size_t)255; };
    size_t off = 0;
    int* deg = (int*)(ws + off);        off += align256((size_t)N * 4);
    int* dpad = (int*)(ws + off);       off += align256((size_t)N * 4);
    float* dinv = (float*)(ws + off);   off += align256((size_t)N * 4);
    int* offs = (int*)(ws + off);       off += align256((size_t)N * 4);
    int* bsum = (int*)(ws + off);       off += align256((size_t)4096);
    int* btotal = (int*)(ws + off);     off += align256((size_t)MAXBUCK * 4);
    int* bstart = (int*)(ws + off);     off += align256((size_t)MAXBUCK * 4);
    int* bcur = (int*)(ws + off);       off += align256((size_t)MAXBUCK * 64); // padded
    u32* bucketed = (u32*)(ws + off);   off += align256((size_t)E * 4);
    size_t metaCap = (size_t)E + (size_t)(PAD - 1) * N + 16;  // +16 prefetch slack
    u32* meta = (u32*)(ws + off);       off += align256(metaCap * 4);
    u32* xb = (u32*)(ws + off);         off += align256((size_t)N * 32 * 4);  // bf16 rows
    u32* hA = (u32*)(ws + off);         off += align256((size_t)N * 32 * 4);
    u32* hB = (u32*)(ws + off);         off += align256((size_t)N * 32 * 4);

    float* out = (float*)d_out;

    const int BLK = 256;
    const int gridE = (E + BLK - 1) / BLK;
    const int gridN = (N + BLK - 1) / BLK;
    const int nb    = (N + SCAN_TILE - 1) / SCAN_TILE;
    const int n8    = N * DFEAT / 8;
    const int gridC = (n8 + BLK - 1) / BLK;
    const int gridProp = (N * 8 + BLK - 1) / BLK;   // 8 threads per node
    const int GR_A = 128;
    const int chunkA = (E + GR_A - 1) / GR_A;

    hipMemsetAsync(deg, 0, (size_t)N * 4, stream);
    hipMemsetAsync(meta, 0, metaCap * 4, stream);   // pads -> src=0, w=0
    k_hist <<<gridE, BLK, 0, stream>>>(col, deg, E);
    k_dinv <<<gridN, BLK, 0, stream>>>(deg, dinv, dpad, N);
    k_scan1<<<nb, SCAN_T, 0, stream>>>(dpad, offs, bsum, N);
    k_scan2<<<1, 64, 0, stream>>>(bsum, nb);
    k_scan3<<<nb, SCAN_T, 0, stream>>>(offs, bsum, N);
    k_bsum <<<NBUCK, 256, 0, stream>>>(deg, btotal, N);
    k_bscan<<<1, MAXBUCK, 0, stream>>>(btotal, bstart, bcur, NBUCK);
    k_bucketA<<<GR_A, BLK, 0, stream>>>(row, col, bcur, bucketed, E, NBUCK, chunkA);
    k_fillB<<<NBUCK, BLK, 0, stream>>>(bucketed, bstart, btotal, offs, dinv, meta, N);
    k_cvt  <<<gridC, BLK, 0, stream>>>(x, xb, n8);

    // k=0: xb -> hA; then ping-pong; k=9 (LAST): -> out in fp32
    u32* bufs[2] = { hA, hB };
    for (int k = 0; k < KSTEPS; ++k) {
        const u32* src = (k == 0) ? xb : bufs[(k + 1) & 1];
        if (k < KSTEPS - 1) {
            k_prop<false><<<gridProp, BLK, 0, stream>>>(offs, dpad, meta, src, x, xb,
                                                        (void*)bufs[k & 1], N);
        } else {
            k_prop<true><<<gridProp, BLK, 0, stream>>>(offs, dpad, meta, src, x, xb,
                                                       (void*)out, N);
        }
    }
    (void)ws_size; (void)n_in; (void)out_size;
}

// Round 10
// 340.684 us; speedup vs baseline: 1.6442x; 1.1549x over previous
//
#include <hip/hip_runtime.h>

constexpr int DFEAT  = 64;
constexpr int KSTEPS = 10;
constexpr float ALPHA = 0.1f;
constexpr int PAD    = 4;       // CSR row length padded to multiple of 4
constexpr int BSHIFT = 8;       // 256 nodes per dst bucket
constexpr int MAXBUCK = 512;    // max buckets (N <= 131072)
constexpr int GR_A   = 128;     // bucketing blocks

constexpr int SCAN_T    = 256;
constexpr int SCAN_I    = 4;
constexpr int SCAN_TILE = SCAN_T * SCAN_I;  // 1024

typedef unsigned int u32;
typedef __attribute__((ext_vector_type(4))) unsigned int u32x4;

// bf16 pack helper (round-to-nearest-even), returns low 16 bits
__device__ inline u32 f2bf(float f) {
    u32 u = __float_as_uint(f);
    return ((u + 0x7fffu + ((u >> 16) & 1u)) >> 16) & 0xFFFFu;
}
__device__ inline float bfLO(u32 v) { return __uint_as_float(v << 16); }
__device__ inline float bfHI(u32 v) { return __uint_as_float(v & 0xFFFF0000u); }

// ---- A1: per-block LDS bucket histogram -> blockhist[block][bucket] ----
__global__ void __launch_bounds__(256) k_hA(
    const int* __restrict__ col, int* __restrict__ blockhist,
    int E, int nb, int chunk) {
    __shared__ int hist[MAXBUCK];
    int t  = threadIdx.x;
    int e0 = blockIdx.x * chunk;
    int e1 = min(E, e0 + chunk);
    for (int b = t; b < MAXBUCK; b += 256) hist[b] = 0;
    __syncthreads();
    for (int e = e0 + t; e < e1; e += 256)
        atomicAdd(&hist[col[e] >> BSHIFT], 1);
    __syncthreads();
    for (int b = t; b < nb; b += 256)
        blockhist[blockIdx.x * MAXBUCK + b] = hist[b];
}

// ---- A2: per bucket, exclusive scan over the GR_A per-block counts ----
__global__ void k_colsum(int* __restrict__ blockhist, int* __restrict__ btotal) {
    __shared__ int s[GR_A];
    int b = blockIdx.x, t = threadIdx.x;     // GR_A threads
    int v = blockhist[t * MAXBUCK + b];
    s[t] = v;
    __syncthreads();
    // Hillis-Steele inclusive scan
    for (int o = 1; o < GR_A; o <<= 1) {
        int u = (t >= o) ? s[t - o] : 0;
        __syncthreads();
        s[t] += u;
        __syncthreads();
    }
    blockhist[t * MAXBUCK + b] = s[t] - v;   // exclusive
    if (t == GR_A - 1) btotal[b] = s[t];
}

// ---- A3: exclusive scan of bucket totals -> bstart ----
__global__ void k_bscan(const int* __restrict__ btotal, int* __restrict__ bstart,
                        int nb) {
    __shared__ int s[MAXBUCK];
    int t = threadIdx.x;
    if (t < nb) s[t] = btotal[t];
    __syncthreads();
    if (t == 0) {
        int acc = 0;
        for (int i = 0; i < nb; ++i) { int v = s[i]; s[i] = acc; acc += v; }
    }
    __syncthreads();
    if (t < nb) bstart[t] = s[t];
}

// ---- A4: write edges into pre-reserved bucket segments (LDS cursors only) ----
__global__ void __launch_bounds__(256) k_hB(
    const int* __restrict__ row, const int* __restrict__ col,
    const int* __restrict__ blockhist, const int* __restrict__ bstart,
    u32* __restrict__ bucketed, int E, int nb, int chunk) {
    __shared__ int cur[MAXBUCK];
    int t  = threadIdx.x;
    int e0 = blockIdx.x * chunk;
    int e1 = min(E, e0 + chunk);
    for (int b = t; b < nb; b += 256)
        cur[b] = bstart[b] + blockhist[blockIdx.x * MAXBUCK + b];
    __syncthreads();
    for (int e = e0 + t; e < e1; e += 256) {
        int c = col[e], r = row[e];
        int rank = atomicAdd(&cur[c >> BSHIFT], 1);
        bucketed[rank] = ((u32)r << BSHIFT) | (u32)(c & ((1 << BSHIFT) - 1));
    }
}

// ---- A5: per-bucket degree count from bucketed; emit dinv + dpad (no global deg) ----
__global__ void __launch_bounds__(256) k_degB(
    const u32* __restrict__ bucketed, const int* __restrict__ bstart,
    const int* __restrict__ btotal, float* __restrict__ dinv,
    int* __restrict__ dpad, int N) {
    __shared__ int cnt[256];
    int b = blockIdx.x, t = threadIdx.x;
    cnt[t] = 0;
    __syncthreads();
    int p0 = bstart[b], p1 = p0 + btotal[b];
    for (int p = p0 + t; p < p1; p += 256)
        atomicAdd(&cnt[bucketed[p] & 255u], 1);
    __syncthreads();
    int node = (b << BSHIFT) + t;
    if (node < N) {
        int d = cnt[t];
        dinv[node] = (d > 0) ? rsqrtf((float)d) : 0.0f;
        dpad[node] = (d + (PAD - 1)) & ~(PAD - 1);
    }
}

// ---- scan phase 1 (exclusive scan of dpad) ----
__global__ void k_scan1(const int* __restrict__ in, int* __restrict__ out,
                        int* __restrict__ bsum, int n) {
    __shared__ int s[SCAN_T];
    int tid  = threadIdx.x;
    int base = blockIdx.x * SCAN_TILE + tid * SCAN_I;
    int v[SCAN_I];
    int sum = 0;
#pragma unroll
    for (int j = 0; j < SCAN_I; ++j) {
        v[j] = (base + j < n) ? in[base + j] : 0;
        sum += v[j];
    }
    s[tid] = sum;
    __syncthreads();
    for (int ofs = 1; ofs < SCAN_T; ofs <<= 1) {
        int t = (tid >= ofs) ? s[tid - ofs] : 0;
        __syncthreads();
        s[tid] += t;
        __syncthreads();
    }
    int excl = (tid == 0) ? 0 : s[tid - 1];
    if (tid == SCAN_T - 1) bsum[blockIdx.x] = s[tid];
#pragma unroll
    for (int j = 0; j < SCAN_I; ++j) {
        if (base + j < n) out[base + j] = excl;
        excl += v[j];
    }
}

// ---- scan phase 2 ----
__global__ void k_scan2(int* __restrict__ bsum, int nb) {
    if (threadIdx.x == 0 && blockIdx.x == 0) {
        int acc = 0;
        for (int i = 0; i < nb; ++i) { int t = bsum[i]; bsum[i] = acc; acc += t; }
    }
}

// ---- scan phase 3: offs += block offset ----
__global__ void k_scan3(int* __restrict__ offs, const int* __restrict__ bsum, int n) {
    int add  = bsum[blockIdx.x];
    int base = blockIdx.x * SCAN_TILE + threadIdx.x * SCAN_I;
#pragma unroll
    for (int j = 0; j < SCAN_I; ++j) {
        int i = base + j;
        if (i < n) offs[i] += add;
    }
}

// ---- pass B: per-bucket CSR fill; LDS cursors, bucket-local meta writes ----
__global__ void __launch_bounds__(256) k_fillB(
    const u32* __restrict__ bucketed, const int* __restrict__ bstart,
    const int* __restrict__ btotal, const int* __restrict__ offs,
    const float* __restrict__ dinv, u32* __restrict__ meta, int N) {
    __shared__ int   lcur[256];
    __shared__ float ldinv[256];
    int b = blockIdx.x, t = threadIdx.x;
    int node = (b << BSHIFT) + t;
    lcur[t]  = (node < N) ? offs[node] : 0;
    ldinv[t] = (node < N) ? dinv[node] : 0.0f;
    __syncthreads();
    int p0 = bstart[b], p1 = p0 + btotal[b];
    for (int p = p0 + t; p < p1; p += 256) {
        u32 v  = bucketed[p];
        int r  = (int)(v >> BSHIFT);
        int cl = (int)(v & 255u);
        int pos = atomicAdd(&lcur[cl], 1);
        float w = dinv[r] * ldinv[cl];            // in [0,1]
        u32 wq = (u32)__float2int_rn(w * 32768.0f);
        if (wq > 32767u) wq = 32767u;
        meta[pos] = (wq << 17) | (u32)r;
    }
}

// ---- x (fp32) -> xb (bf16 packed, 32 u32 per row) ----
__global__ void k_cvt(const float* __restrict__ x, u32* __restrict__ xb, int n8) {
    int stride = gridDim.x * blockDim.x;
    const float4* x4 = (const float4*)x;
    u32x4* o4 = (u32x4*)xb;
    for (int i = blockIdx.x * blockDim.x + threadIdx.x; i < n8; i += stride) {
        float4 a = x4[2 * i], b = x4[2 * i + 1];
        u32x4 o;
        o.x = (f2bf(a.y) << 16) | f2bf(a.x);
        o.y = (f2bf(a.w) << 16) | f2bf(a.z);
        o.z = (f2bf(b.y) << 16) | f2bf(b.x);
        o.w = (f2bf(b.w) << 16) | f2bf(b.z);
        o4[i] = o;
    }
}

// ---- propagate: one 8-lane group per dst node; lane l covers features l*8..l*8+7.
template<bool LAST>
__global__ void __launch_bounds__(256) k_prop(
    const int* __restrict__ offs, const int* __restrict__ dpad,
    const u32* __restrict__ meta, const u32* __restrict__ hsrc,
    const float* __restrict__ x, const u32* __restrict__ xb,
    void* __restrict__ hdst, int N) {
    int gid = (int)((blockIdx.x * blockDim.x + threadIdx.x) >> 3);  // node id
    int l   = threadIdx.x & 7;                                      // lane in group
    if (gid >= N) return;
    int j   = offs[gid];
    int end = j + dpad[gid];          // multiple of 4

    const u32x4* h4 = (const u32x4*)hsrc;   // row r = h4[r*8 .. r*8+7]
    float a0 = 0.f, a1 = 0.f, a2 = 0.f, a3 = 0.f,
          a4 = 0.f, a5 = 0.f, a6 = 0.f, a7 = 0.f;

    if (j < end) {
        u32x4 mq = *(const u32x4*)&meta[j];           // 4 edges (broadcast in group)
        while (j < end) {
            int jn = j + 4;
            u32x4 mqn = *(const u32x4*)&meta[jn];     // prefetch (slack-allocated)
            u32x4 q0 = h4[(size_t)(mq.x & 0x1FFFFu) * 8 + l];
            u32x4 q1 = h4[(size_t)(mq.y & 0x1FFFFu) * 8 + l];
            u32x4 q2 = h4[(size_t)(mq.z & 0x1FFFFu) * 8 + l];
            u32x4 q3 = h4[(size_t)(mq.w & 0x1FFFFu) * 8 + l];
            float w0 = (float)(mq.x >> 17) * (1.0f / 32768.0f);
            float w1 = (float)(mq.y >> 17) * (1.0f / 32768.0f);
            float w2 = (float)(mq.z >> 17) * (1.0f / 32768.0f);
            float w3 = (float)(mq.w >> 17) * (1.0f / 32768.0f);
            a0 += w0 * bfLO(q0.x); a1 += w0 * bfHI(q0.x);
            a2 += w0 * bfLO(q0.y); a3 += w0 * bfHI(q0.y);
            a4 += w0 * bfLO(q0.z); a5 += w0 * bfHI(q0.z);
            a6 += w0 * bfLO(q0.w); a7 += w0 * bfHI(q0.w);
            a0 += w1 * bfLO(q1.x); a1 += w1 * bfHI(q1.x);
            a2 += w1 * bfLO(q1.y); a3 += w1 * bfHI(q1.y);
            a4 += w1 * bfLO(q1.z); a5 += w1 * bfHI(q1.z);
            a6 += w1 * bfLO(q1.w); a7 += w1 * bfHI(q1.w);
            a0 += w2 * bfLO(q2.x); a1 += w2 * bfHI(q2.x);
            a2 += w2 * bfLO(q2.y); a3 += w2 * bfHI(q2.y);
            a4 += w2 * bfLO(q2.z); a5 += w2 * bfHI(q2.z);
            a6 += w2 * bfLO(q2.w); a7 += w2 * bfHI(q2.w);
            a0 += w3 * bfLO(q3.x); a1 += w3 * bfHI(q3.x);
            a2 += w3 * bfLO(q3.y); a3 += w3 * bfHI(q3.y);
            a4 += w3 * bfLO(q3.z); a5 += w3 * bfHI(q3.z);
            a6 += w3 * bfLO(q3.w); a7 += w3 * bfHI(q3.w);
            mq = mqn; j = jn;
        }
    }

    if (LAST) {
        size_t base = (size_t)gid * DFEAT + (size_t)l * 8;
        float4 xa = *(const float4*)&x[base];
        float4 xc = *(const float4*)&x[base + 4];
        float r0 = (1.0f - ALPHA) * a0 + ALPHA * xa.x;
        float r1 = (1.0f - ALPHA) * a1 + ALPHA * xa.y;
        float r2 = (1.0f - ALPHA) * a2 + ALPHA * xa.z;
        float r3 = (1.0f - ALPHA) * a3 + ALPHA * xa.w;
        float r4 = (1.0f - ALPHA) * a4 + ALPHA * xc.x;
        float r5 = (1.0f - ALPHA) * a5 + ALPHA * xc.y;
        float r6 = (1.0f - ALPHA) * a6 + ALPHA * xc.z;
        float r7 = (1.0f - ALPHA) * a7 + ALPHA * xc.w;
        float* o = (float*)hdst;
        *(float4*)&o[base]     = make_float4(r0, r1, r2, r3);
        *(float4*)&o[base + 4] = make_float4(r4, r5, r6, r7);
    } else {
        u32x4 t = ((const u32x4*)xb)[(size_t)gid * 8 + l];
        float r0 = (1.0f - ALPHA) * a0 + ALPHA * bfLO(t.x);
        float r1 = (1.0f - ALPHA) * a1 + ALPHA * bfHI(t.x);
        float r2 = (1.0f - ALPHA) * a2 + ALPHA * bfLO(t.y);
        float r3 = (1.0f - ALPHA) * a3 + ALPHA * bfHI(t.y);
        float r4 = (1.0f - ALPHA) * a4 + ALPHA * bfLO(t.z);
        float r5 = (1.0f - ALPHA) * a5 + ALPHA * bfHI(t.z);
        float r6 = (1.0f - ALPHA) * a6 + ALPHA * bfLO(t.w);
        float r7 = (1.0f - ALPHA) * a7 + ALPHA * bfHI(t.w);
        u32x4 o;
        o.x = (f2bf(r1) << 16) | f2bf(r0);
        o.y = (f2bf(r3) << 16) | f2bf(r2);
        o.z = (f2bf(r5) << 16) | f2bf(r4);
        o.w = (f2bf(r7) << 16) | f2bf(r6);
        ((u32x4*)hdst)[(size_t)gid * 8 + l] = o;
    }
}

extern "C" void kernel_launch(void* const* d_in, const int* in_sizes, int n_in,
                              void* d_out, int out_size, void* d_ws, size_t ws_size,
                              hipStream_t stream) {
    const float* x  = (const float*)d_in[0];
    const int*   ei = (const int*)d_in[1];
    const int N = in_sizes[0] / DFEAT;   // 100000 (< 2^17, fits packed src)
    const int E = in_sizes[1] / 2;
    const int* row = ei;       // sources
    const int* col = ei + E;   // destinations

    const int NBUCK = (N + ((1 << BSHIFT) - 1)) >> BSHIFT;   // 391 (<= MAXBUCK)

    char* ws = (char*)d_ws;
    auto align256 = [](size_t v) { return (v + 255) & ~(size_t)255; };
    size_t off = 0;
    int* dpad = (int*)(ws + off);       off += align256((size_t)N * 4);
    float* dinv = (float*)(ws + off);   off += align256((size_t)N * 4);
    int* offs = (int*)(ws + off);       off += align256((size_t)N * 4);
    int* bsum = (int*)(ws + off);       off += align256((size_t)4096);
    int* btotal = (int*)(ws + off);     off += align256((size_t)MAXBUCK * 4);
    int* bstart = (int*)(ws + off);     off += align256((size_t)MAXBUCK * 4);
    int* blockhist = (int*)(ws + off);  off += align256((size_t)GR_A * MAXBUCK * 4);
    u32* bucketed = (u32*)(ws + off);   off += align256((size_t)E * 4);
    size_t metaCap = (size_t)E + (size_t)(PAD - 1) * N + 16;  // +16 prefetch slack
    u32* meta = (u32*)(ws + off);       off += align256(metaCap * 4);
    u32* xb = (u32*)(ws + off);         off += align256((size_t)N * 32 * 4);  // bf16 rows
    u32* hA = (u32*)(ws + off);         off += align256((size_t)N * 32 * 4);
    u32* hB = (u32*)(ws + off);         off += align256((size_t)N * 32 * 4);

    float* out = (float*)d_out;

    const int BLK = 256;
    const int nb    = (N + SCAN_TILE - 1) / SCAN_TILE;
    const int n8    = N * DFEAT / 8;
    const int gridC = (n8 + BLK - 1) / BLK;
    const int gridProp = (N * 8 + BLK - 1) / BLK;   // 8 threads per node
    const int chunkA = (E + GR_A - 1) / GR_A;

    hipMemsetAsync(meta, 0, metaCap * 4, stream);   // pads -> src=0, w=0
    k_hA    <<<GR_A, BLK, 0, stream>>>(col, blockhist, E, NBUCK, chunkA);
    k_colsum<<<NBUCK, GR_A, 0, stream>>>(blockhist, btotal);
    k_bscan <<<1, MAXBUCK, 0, stream>>>(btotal, bstart, NBUCK);
    k_hB    <<<GR_A, BLK, 0, stream>>>(row, col, blockhist, bstart, bucketed,
                                       E, NBUCK, chunkA);
    k_degB  <<<NBUCK, BLK, 0, stream>>>(bucketed, bstart, btotal, dinv, dpad, N);
    k_scan1 <<<nb, SCAN_T, 0, stream>>>(dpad, offs, bsum, N);
    k_scan2 <<<1, 64, 0, stream>>>(bsum, nb);
    k_scan3 <<<nb, SCAN_T, 0, stream>>>(offs, bsum, N);
    k_fillB <<<NBUCK, BLK, 0, stream>>>(bucketed, bstart, btotal, offs, dinv, meta, N);
    k_cvt   <<<gridC, BLK, 0, stream>>>(x, xb, n8);

    // k=0: xb -> hA; then ping-pong; k=9 (LAST): -> out in fp32
    u32* bufs[2] = { hA, hB };
    for (int k = 0; k < KSTEPS; ++k) {
        const u32* src = (k == 0) ? xb : bufs[(k + 1) & 1];
        if (k < KSTEPS - 1) {
            k_prop<false><<<gridProp, BLK, 0, stream>>>(offs, dpad, meta, src, x, xb,
                                                        (void*)bufs[k & 1], N);
        } else {
            k_prop<true><<<gridProp, BLK, 0, stream>>>(offs, dpad, meta, src, x, xb,
                                                       (void*)out, N);
        }
    }
    (void)ws_size; (void)n_in; (void)out_size;
}

// Round 11
// 334.055 us; speedup vs baseline: 1.6768x; 1.0198x over previous
//
#include <hip/hip_runtime.h>

constexpr int DFEAT  = 64;
constexpr int KSTEPS = 10;
constexpr float ALPHA = 0.1f;
constexpr int PAD    = 8;       // CSR row length padded to multiple of 8
constexpr int BSHIFT = 8;       // 256 nodes per dst bucket
constexpr int MAXBUCK = 512;    // max buckets (N <= 131072)
constexpr int GR_A   = 128;     // bucketing blocks

constexpr int SCAN_T    = 256;
constexpr int SCAN_I    = 4;
constexpr int SCAN_TILE = SCAN_T * SCAN_I;  // 1024

typedef unsigned int u32;
typedef __attribute__((ext_vector_type(4))) unsigned int u32x4;

// bf16 pack helper (round-to-nearest-even), returns low 16 bits
__device__ inline u32 f2bf(float f) {
    u32 u = __float_as_uint(f);
    return ((u + 0x7fffu + ((u >> 16) & 1u)) >> 16) & 0xFFFFu;
}
__device__ inline float bfLO(u32 v) { return __uint_as_float(v << 16); }
__device__ inline float bfHI(u32 v) { return __uint_as_float(v & 0xFFFF0000u); }

// ---- A1 (fused): blocks [0,GR_A): LDS bucket histogram; rest: x->bf16 cvt ----
__global__ void __launch_bounds__(256) k_hA_cvt(
    const int* __restrict__ col, int* __restrict__ blockhist,
    int E, int nb, int chunk,
    const float* __restrict__ x, u32* __restrict__ xb, int n8) {
    __shared__ int hist[MAXBUCK];
    int t = threadIdx.x;
    if ((int)blockIdx.x < GR_A) {
        int e0 = blockIdx.x * chunk;
        int e1 = min(E, e0 + chunk);
        for (int b = t; b < MAXBUCK; b += 256) hist[b] = 0;
        __syncthreads();
        for (int e = e0 + t; e < e1; e += 256)
            atomicAdd(&hist[col[e] >> BSHIFT], 1);
        __syncthreads();
        for (int b = t; b < nb; b += 256)
            blockhist[blockIdx.x * MAXBUCK + b] = hist[b];
    } else {
        int stride = (gridDim.x - GR_A) * blockDim.x;
        const float4* x4 = (const float4*)x;
        u32x4* o4 = (u32x4*)xb;
        for (int i = (blockIdx.x - GR_A) * blockDim.x + t; i < n8; i += stride) {
            float4 a = x4[2 * i], b = x4[2 * i + 1];
            u32x4 o;
            o.x = (f2bf(a.y) << 16) | f2bf(a.x);
            o.y = (f2bf(a.w) << 16) | f2bf(a.z);
            o.z = (f2bf(b.y) << 16) | f2bf(b.x);
            o.w = (f2bf(b.w) << 16) | f2bf(b.z);
            o4[i] = o;
        }
    }
}

// ---- A2: per bucket, exclusive scan over the GR_A per-block counts ----
__global__ void k_colsum(int* __restrict__ blockhist, int* __restrict__ btotal) {
    __shared__ int s[GR_A];
    int b = blockIdx.x, t = threadIdx.x;     // GR_A threads
    int v = blockhist[t * MAXBUCK + b];
    s[t] = v;
    __syncthreads();
    for (int o = 1; o < GR_A; o <<= 1) {
        int u = (t >= o) ? s[t - o] : 0;
        __syncthreads();
        s[t] += u;
        __syncthreads();
    }
    blockhist[t * MAXBUCK + b] = s[t] - v;   // exclusive
    if (t == GR_A - 1) btotal[b] = s[t];
}

// ---- A3: exclusive scan of bucket totals -> bstart ----
__global__ void k_bscan(const int* __restrict__ btotal, int* __restrict__ bstart,
                        int nb) {
    __shared__ int s[MAXBUCK];
    int t = threadIdx.x;
    if (t < nb) s[t] = btotal[t];
    __syncthreads();
    if (t == 0) {
        int acc = 0;
        for (int i = 0; i < nb; ++i) { int v = s[i]; s[i] = acc; acc += v; }
    }
    __syncthreads();
    if (t < nb) bstart[t] = s[t];
}

// ---- A4: write edges into pre-reserved bucket segments (LDS cursors only) ----
__global__ void __launch_bounds__(256) k_hB(
    const int* __restrict__ row, const int* __restrict__ col,
    const int* __restrict__ blockhist, const int* __restrict__ bstart,
    u32* __restrict__ bucketed, int E, int nb, int chunk) {
    __shared__ int cur[MAXBUCK];
    int t  = threadIdx.x;
    int e0 = blockIdx.x * chunk;
    int e1 = min(E, e0 + chunk);
    for (int b = t; b < nb; b += 256)
        cur[b] = bstart[b] + blockhist[blockIdx.x * MAXBUCK + b];
    __syncthreads();
    for (int e = e0 + t; e < e1; e += 256) {
        int c = col[e], r = row[e];
        int rank = atomicAdd(&cur[c >> BSHIFT], 1);
        bucketed[rank] = ((u32)r << BSHIFT) | (u32)(c & ((1 << BSHIFT) - 1));
    }
}

// ---- A5: per-bucket degree count from bucketed; emit dinv + dpad ----
__global__ void __launch_bounds__(256) k_degB(
    const u32* __restrict__ bucketed, const int* __restrict__ bstart,
    const int* __restrict__ btotal, float* __restrict__ dinv,
    int* __restrict__ dpad, int N) {
    __shared__ int cnt[256];
    int b = blockIdx.x, t = threadIdx.x;
    cnt[t] = 0;
    __syncthreads();
    int p0 = bstart[b], p1 = p0 + btotal[b];
    for (int p = p0 + t; p < p1; p += 256)
        atomicAdd(&cnt[bucketed[p] & 255u], 1);
    __syncthreads();
    int node = (b << BSHIFT) + t;
    if (node < N) {
        int d = cnt[t];
        dinv[node] = (d > 0) ? rsqrtf((float)d) : 0.0f;
        dpad[node] = (d + (PAD - 1)) & ~(PAD - 1);
    }
}

// ---- scan phase 1 (exclusive scan of dpad) ----
__global__ void k_scan1(const int* __restrict__ in, int* __restrict__ out,
                        int* __restrict__ bsum, int n) {
    __shared__ int s[SCAN_T];
    int tid  = threadIdx.x;
    int base = blockIdx.x * SCAN_TILE + tid * SCAN_I;
    int v[SCAN_I];
    int sum = 0;
#pragma unroll
    for (int j = 0; j < SCAN_I; ++j) {
        v[j] = (base + j < n) ? in[base + j] : 0;
        sum += v[j];
    }
    s[tid] = sum;
    __syncthreads();
    for (int ofs = 1; ofs < SCAN_T; ofs <<= 1) {
        int t = (tid >= ofs) ? s[tid - ofs] : 0;
        __syncthreads();
        s[tid] += t;
        __syncthreads();
    }
    int excl = (tid == 0) ? 0 : s[tid - 1];
    if (tid == SCAN_T - 1) bsum[blockIdx.x] = s[tid];
#pragma unroll
    for (int j = 0; j < SCAN_I; ++j) {
        if (base + j < n) out[base + j] = excl;
        excl += v[j];
    }
}

// ---- scan phase 3: offs += prefix of bsum (scan2 inlined per block) ----
__global__ void k_scan3(int* __restrict__ offs, const int* __restrict__ bsum, int n) {
    __shared__ int s_add;
    if (threadIdx.x == 0) {
        int acc = 0;
        for (int i = 0; i < (int)blockIdx.x; ++i) acc += bsum[i];
        s_add = acc;
    }
    __syncthreads();
    int add  = s_add;
    int base = blockIdx.x * SCAN_TILE + threadIdx.x * SCAN_I;
#pragma unroll
    for (int j = 0; j < SCAN_I; ++j) {
        int i = base + j;
        if (i < n) offs[i] += add;
    }
}

// ---- pass B: per-bucket CSR fill; LDS cursors, bucket-local meta writes ----
__global__ void __launch_bounds__(256) k_fillB(
    const u32* __restrict__ bucketed, const int* __restrict__ bstart,
    const int* __restrict__ btotal, const int* __restrict__ offs,
    const float* __restrict__ dinv, u32* __restrict__ meta, int N) {
    __shared__ int   lcur[256];
    __shared__ float ldinv[256];
    int b = blockIdx.x, t = threadIdx.x;
    int node = (b << BSHIFT) + t;
    lcur[t]  = (node < N) ? offs[node] : 0;
    ldinv[t] = (node < N) ? dinv[node] : 0.0f;
    __syncthreads();
    int p0 = bstart[b], p1 = p0 + btotal[b];
    for (int p = p0 + t; p < p1; p += 256) {
        u32 v  = bucketed[p];
        int r  = (int)(v >> BSHIFT);
        int cl = (int)(v & 255u);
        int pos = atomicAdd(&lcur[cl], 1);
        float w = dinv[r] * ldinv[cl];            // in [0,1]
        u32 wq = (u32)__float2int_rn(w * 32768.0f);
        if (wq > 32767u) wq = 32767u;
        meta[pos] = (wq << 17) | (u32)r;
    }
}

// ---- propagate: one 8-lane group per dst node; lane l covers features l*8..l*8+7.
// PAD=8 rows -> uniform 8-deep MLP loop, double-buffered meta, no tail.
template<bool LAST>
__global__ void __launch_bounds__(256) k_prop(
    const int* __restrict__ offs, const int* __restrict__ dpad,
    const u32* __restrict__ meta, const u32* __restrict__ hsrc,
    const float* __restrict__ x, const u32* __restrict__ xb,
    void* __restrict__ hdst, int N) {
    int gid = (int)((blockIdx.x * blockDim.x + threadIdx.x) >> 3);  // node id
    int l   = threadIdx.x & 7;                                      // lane in group
    if (gid >= N) return;
    int j   = offs[gid];
    int end = j + dpad[gid];          // multiple of 8 (or 0)

    const u32x4* h4 = (const u32x4*)hsrc;   // row r = h4[r*8 .. r*8+7]
    float a0 = 0.f, a1 = 0.f, a2 = 0.f, a3 = 0.f,
          a4 = 0.f, a5 = 0.f, a6 = 0.f, a7 = 0.f;

    if (j < end) {
        u32x4 mA = *(const u32x4*)&meta[j];
        u32x4 mB = *(const u32x4*)&meta[j + 4];
        while (j < end) {
            int jn = j + 8;
            // 8 independent gathers in flight
            u32x4 q0 = h4[(size_t)(mA.x & 0x1FFFFu) * 8 + l];
            u32x4 q1 = h4[(size_t)(mA.y & 0x1FFFFu) * 8 + l];
            u32x4 q2 = h4[(size_t)(mA.z & 0x1FFFFu) * 8 + l];
            u32x4 q3 = h4[(size_t)(mA.w & 0x1FFFFu) * 8 + l];
            u32x4 q4 = h4[(size_t)(mB.x & 0x1FFFFu) * 8 + l];
            u32x4 q5 = h4[(size_t)(mB.y & 0x1FFFFu) * 8 + l];
            u32x4 q6 = h4[(size_t)(mB.z & 0x1FFFFu) * 8 + l];
            u32x4 q7 = h4[(size_t)(mB.w & 0x1FFFFu) * 8 + l];
            // prefetch next meta (slack-allocated past array end)
            u32x4 mA2 = *(const u32x4*)&meta[jn];
            u32x4 mB2 = *(const u32x4*)&meta[jn + 4];
            float w0 = (float)(mA.x >> 17) * (1.0f / 32768.0f);
            float w1 = (float)(mA.y >> 17) * (1.0f / 32768.0f);
            float w2 = (float)(mA.z >> 17) * (1.0f / 32768.0f);
            float w3 = (float)(mA.w >> 17) * (1.0f / 32768.0f);
            float w4 = (float)(mB.x >> 17) * (1.0f / 32768.0f);
            float w5 = (float)(mB.y >> 17) * (1.0f / 32768.0f);
            float w6 = (float)(mB.z >> 17) * (1.0f / 32768.0f);
            float w7 = (float)(mB.w >> 17) * (1.0f / 32768.0f);
            a0 += w0 * bfLO(q0.x); a1 += w0 * bfHI(q0.x);
            a2 += w0 * bfLO(q0.y); a3 += w0 * bfHI(q0.y);
            a4 += w0 * bfLO(q0.z); a5 += w0 * bfHI(q0.z);
            a6 += w0 * bfLO(q0.w); a7 += w0 * bfHI(q0.w);
            a0 += w1 * bfLO(q1.x); a1 += w1 * bfHI(q1.x);
            a2 += w1 * bfLO(q1.y); a3 += w1 * bfHI(q1.y);
            a4 += w1 * bfLO(q1.z); a5 += w1 * bfHI(q1.z);
            a6 += w1 * bfLO(q1.w); a7 += w1 * bfHI(q1.w);
            a0 += w2 * bfLO(q2.x); a1 += w2 * bfHI(q2.x);
            a2 += w2 * bfLO(q2.y); a3 += w2 * bfHI(q2.y);
            a4 += w2 * bfLO(q2.z); a5 += w2 * bfHI(q2.z);
            a6 += w2 * bfLO(q2.w); a7 += w2 * bfHI(q2.w);
            a0 += w3 * bfLO(q3.x); a1 += w3 * bfHI(q3.x);
            a2 += w3 * bfLO(q3.y); a3 += w3 * bfHI(q3.y);
            a4 += w3 * bfLO(q3.z); a5 += w3 * bfHI(q3.z);
            a6 += w3 * bfLO(q3.w); a7 += w3 * bfHI(q3.w);
            a0 += w4 * bfLO(q4.x); a1 += w4 * bfHI(q4.x);
            a2 += w4 * bfLO(q4.y); a3 += w4 * bfHI(q4.y);
            a4 += w4 * bfLO(q4.z); a5 += w4 * bfHI(q4.z);
            a6 += w4 * bfLO(q4.w); a7 += w4 * bfHI(q4.w);
            a0 += w5 * bfLO(q5.x); a1 += w5 * bfHI(q5.x);
            a2 += w5 * bfLO(q5.y); a3 += w5 * bfHI(q5.y);
            a4 += w5 * bfLO(q5.z); a5 += w5 * bfHI(q5.z);
            a6 += w5 * bfLO(q5.w); a7 += w5 * bfHI(q5.w);
            a0 += w6 * bfLO(q6.x); a1 += w6 * bfHI(q6.x);
            a2 += w6 * bfLO(q6.y); a3 += w6 * bfHI(q6.y);
            a4 += w6 * bfLO(q6.z); a5 += w6 * bfHI(q6.z);
            a6 += w6 * bfLO(q6.w); a7 += w6 * bfHI(q6.w);
            a0 += w7 * bfLO(q7.x); a1 += w7 * bfHI(q7.x);
            a2 += w7 * bfLO(q7.y); a3 += w7 * bfHI(q7.y);
            a4 += w7 * bfLO(q7.z); a5 += w7 * bfHI(q7.z);
            a6 += w7 * bfLO(q7.w); a7 += w7 * bfHI(q7.w);
            mA = mA2; mB = mB2; j = jn;
        }
    }

    if (LAST) {
        size_t base = (size_t)gid * DFEAT + (size_t)l * 8;
        float4 xa = *(const float4*)&x[base];
        float4 xc = *(const float4*)&x[base + 4];
        float r0 = (1.0f - ALPHA) * a0 + ALPHA * xa.x;
        float r1 = (1.0f - ALPHA) * a1 + ALPHA * xa.y;
        float r2 = (1.0f - ALPHA) * a2 + ALPHA * xa.z;
        float r3 = (1.0f - ALPHA) * a3 + ALPHA * xa.w;
        float r4 = (1.0f - ALPHA) * a4 + ALPHA * xc.x;
        float r5 = (1.0f - ALPHA) * a5 + ALPHA * xc.y;
        float r6 = (1.0f - ALPHA) * a6 + ALPHA * xc.z;
        float r7 = (1.0f - ALPHA) * a7 + ALPHA * xc.w;
        float* o = (float*)hdst;
        *(float4*)&o[base]     = make_float4(r0, r1, r2, r3);
        *(float4*)&o[base + 4] = make_float4(r4, r5, r6, r7);
    } else {
        u32x4 t = ((const u32x4*)xb)[(size_t)gid * 8 + l];
        float r0 = (1.0f - ALPHA) * a0 + ALPHA * bfLO(t.x);
        float r1 = (1.0f - ALPHA) * a1 + ALPHA * bfHI(t.x);
        float r2 = (1.0f - ALPHA) * a2 + ALPHA * bfLO(t.y);
        float r3 = (1.0f - ALPHA) * a3 + ALPHA * bfHI(t.y);
        float r4 = (1.0f - ALPHA) * a4 + ALPHA * bfLO(t.z);
        float r5 = (1.0f - ALPHA) * a5 + ALPHA * bfHI(t.z);
        float r6 = (1.0f - ALPHA) * a6 + ALPHA * bfLO(t.w);
        float r7 = (1.0f - ALPHA) * a7 + ALPHA * bfHI(t.w);
        u32x4 o;
        o.x = (f2bf(r1) << 16) | f2bf(r0);
        o.y = (f2bf(r3) << 16) | f2bf(r2);
        o.z = (f2bf(r5) << 16) | f2bf(r4);
        o.w = (f2bf(r7) << 16) | f2bf(r6);
        ((u32x4*)hdst)[(size_t)gid * 8 + l] = o;
    }
}

extern "C" void kernel_launch(void* const* d_in, const int* in_sizes, int n_in,
                              void* d_out, int out_size, void* d_ws, size_t ws_size,
                              hipStream_t stream) {
    const float* x  = (const float*)d_in[0];
    const int*   ei = (const int*)d_in[1];
    const int N = in_sizes[0] / DFEAT;   // 100000 (< 2^17, fits packed src)
    const int E = in_sizes[1] / 2;
    const int* row = ei;       // sources
    const int* col = ei + E;   // destinations

    const int NBUCK = (N + ((1 << BSHIFT) - 1)) >> BSHIFT;   // 391 (<= MAXBUCK)

    char* ws = (char*)d_ws;
    auto align256 = [](size_t v) { return (v + 255) & ~(size_t)255; };
    size_t off = 0;
    int* dpad = (int*)(ws + off);       off += align256((size_t)N * 4);
    float* dinv = (float*)(ws + off);   off += align256((size_t)N * 4);
    int* offs = (int*)(ws + off);       off += align256((size_t)N * 4);
    int* bsum = (int*)(ws + off);       off += align256((size_t)4096);
    int* btotal = (int*)(ws + off);     off += align256((size_t)MAXBUCK * 4);
    int* bstart = (int*)(ws + off);     off += align256((size_t)MAXBUCK * 4);
    int* blockhist = (int*)(ws + off);  off += align256((size_t)GR_A * MAXBUCK * 4);
    u32* bucketed = (u32*)(ws + off);   off += align256((size_t)E * 4);
    size_t metaCap = (size_t)E + (size_t)(PAD - 1) * N + 32;  // +32 prefetch slack
    u32* meta = (u32*)(ws + off);       off += align256(metaCap * 4);
    u32* xb = (u32*)(ws + off);         off += align256((size_t)N * 32 * 4);  // bf16 rows
    u32* hA = (u32*)(ws + off);         off += align256((size_t)N * 32 * 4);
    u32* hB = (u32*)(ws + off);         off += align256((size_t)N * 32 * 4);

    float* out = (float*)d_out;

    const int BLK = 256;
    const int nb    = (N + SCAN_TILE - 1) / SCAN_TILE;
    const int n8    = N * DFEAT / 8;
    const int gridC = (n8 + BLK - 1) / BLK;
    const int gridProp = (N * 8 + BLK - 1) / BLK;   // 8 threads per node
    const int chunkA = (E + GR_A - 1) / GR_A;

    hipMemsetAsync(meta, 0, metaCap * 4, stream);   // pads -> src=0, w=0
    k_hA_cvt<<<GR_A + gridC, BLK, 0, stream>>>(col, blockhist, E, NBUCK, chunkA,
                                               x, xb, n8);
    k_colsum<<<NBUCK, GR_A, 0, stream>>>(blockhist, btotal);
    k_bscan <<<1, MAXBUCK, 0, stream>>>(btotal, bstart, NBUCK);
    k_hB    <<<GR_A, BLK, 0, stream>>>(row, col, blockhist, bstart, bucketed,
                                       E, NBUCK, chunkA);
    k_degB  <<<NBUCK, BLK, 0, stream>>>(bucketed, bstart, btotal, dinv, dpad, N);
    k_scan1 <<<nb, SCAN_T, 0, stream>>>(dpad, offs, bsum, N);
    k_scan3 <<<nb, SCAN_T, 0, stream>>>(offs, bsum, N);
    k_fillB <<<NBUCK, BLK, 0, stream>>>(bucketed, bstart, btotal, offs, dinv, meta, N);

    // k=0: xb -> hA; then ping-pong; k=9 (LAST): -> out in fp32
    u32* bufs[2] = { hA, hB };
    for (int k = 0; k < KSTEPS; ++k) {
        const u32* src = (k == 0) ? xb : bufs[(k + 1) & 1];
        if (k < KSTEPS - 1) {
            k_prop<false><<<gridProp, BLK, 0, stream>>>(offs, dpad, meta, src, x, xb,
                                                        (void*)bufs[k & 1], N);
        } else {
            k_prop<true><<<gridProp, BLK, 0, stream>>>(offs, dpad, meta, src, x, xb,
                                                       (void*)out, N);
        }
    }
    (void)ws_size; (void)n_in; (void)out_size;
}